// Round 16
// baseline (17.655 us; speedup 1.0000x reference)
//
#include <hip/hip_runtime.h>

// Problem constants (fixed by the bench: B=8, L=512, T=4096, D=512).
constexpr int B = 8;
constexpr int L = 512;
constexpr int D = 512;
constexpr int T = 4096;
constexpr int ROWS = 8;                   // d-rows per block (contiguous 128 KB span)

constexpr int OUT_REP = B * D * T;        // offset of repeats in d_out
constexpr int OUT_LAT = OUT_REP + B * L;  // offset of latent_lengths

// R16: 1024-thread blocks, ROWS=8 -> 512 blocks x 16 waves = 2 blocks/CU,
// 32 waves/CU (full occupancy) with a 128 KB contiguous span per block.
// Payload simplifies: one 8 B LUT read per thread (4 t-indices), reused
// across all 8 rows; each store instruction is a block-wide 16 KB row sweep.
__global__ __launch_bounds__(1024, 8) void encoder_expand_kernel(
    const float* __restrict__ enc,   // (B, D, L)
    const float* __restrict__ dur,   // (B, L)
    float* __restrict__ out)         // [expanded (B,D,T) | repeats (B,L) | latent (B)]
{
    const int bid = blockIdx.x;
    const int b   = bid >> 6;               // 0..7
    const int rp  = bid & 63;               // row group (d = 8*rp .. 8*rp+7)
    const int tid = threadIdx.x;            // 0..1023
    const int lane = tid & 63;
    const int wave = tid >> 6;              // 0..15

    __shared__ unsigned short lut[T];       // 8 KB   t -> l, 0xFFFF = past end
    __shared__ float rows[ROWS * L];        // 16 KB  staged enc rows
    __shared__ int wave_tot[16];

    // ---- issue global loads first (independent) ----
    const float dv = dur[b * L + (tid & 511)];   // low 512 threads own the scan
    const float* encp = enc + ((size_t)b * D + ROWS * rp) * L;  // 8 rows, contiguous
    const float4 rv = reinterpret_cast<const float4*>(encp)[tid];  // 16 KB coalesced

    // ---- init LUT sentinel (1024 x 8 B) while loads are in flight ----
    reinterpret_cast<uint2*>(lut)[tid] = make_uint2(0xFFFFFFFFu, 0xFFFFFFFFu);

    // ---- stage enc rows ----
    reinterpret_cast<float4*>(rows)[tid] = rv;

    // ---- repeats + scan over L=512 (1 elem/thread, low 8 waves carry it) ----
    const int r = (tid < 512) ? (int)floorf(dv + 0.5f) : 0;

    int scan = r;                           // wave-level inclusive scan
    #pragma unroll
    for (int off = 1; off < 64; off <<= 1) {
        int n = __shfl_up(scan, off, 64);
        if (lane >= off) scan += n;
    }
    if (lane == 63) wave_tot[wave] = scan;
    __syncthreads();                        // lut init + rows + wave_tot visible

    int wpre = 0;
    #pragma unroll
    for (int w = 0; w < 16; ++w) wpre += (w < wave) ? wave_tot[w] : 0;
    int k = wpre + scan - r;                // exclusive prefix = t-start of l's span
    int total = 0;
    #pragma unroll
    for (int w = 0; w < 16; ++w) total += wave_tot[w];

    // ---- scatter: each l (= tid < 512) writes its own span ----
    for (int q = 0; q < r; ++q, ++k) if (k < T) lut[k] = (unsigned short)tid;

    // ---- side outputs (one block per batch) ----
    if (rp == 0 && tid < 512) {
        out[OUT_REP + b * L + tid] = (float)r;
        if (tid == 0) out[OUT_LAT + b] = (float)total;
    }
    __syncthreads();                        // scatter done

    // ---- payload: one 8 B LUT read; 8 rows x block-wide 16 KB row sweep ----
    float4* out4 = reinterpret_cast<float4*>(out + ((size_t)b * D + ROWS * rp) * T);

    const uint2 lu = *reinterpret_cast<const uint2*>(&lut[4 * tid]);
    const int la = lu.x & 0xffff, lb = lu.x >> 16;
    const int lc = lu.y & 0xffff, ld = lu.y >> 16;
    const int ia = la & 511, ib = lb & 511, ic = lc & 511, id = ld & 511;

    #pragma unroll
    for (int rr = 0; rr < ROWS; ++rr) {
        const float* rowp = rows + rr * L;
        float4 v;
        v.x = rowp[ia];                     // monotone l across lanes: ~2-way banks
        v.y = rowp[ib];
        v.z = rowp[ic];
        v.w = rowp[id];
        if (la == 0xffff) v.x = 0.0f;
        if (lb == 0xffff) v.y = 0.0f;
        if (lc == 0xffff) v.z = 0.0f;
        if (ld == 0xffff) v.w = 0.0f;
        out4[rr * 1024 + tid] = v;          // block-wide 16 KB sequential store
    }
}

extern "C" void kernel_launch(void* const* d_in, const int* in_sizes, int n_in,
                              void* d_out, int out_size, void* d_ws, size_t ws_size,
                              hipStream_t stream) {
    const float* enc = (const float*)d_in[0];   // (B, D, L) fp32
    const float* dur = (const float*)d_in[1];   // (B, L)    fp32
    float* out = (float*)d_out;
    encoder_expand_kernel<<<dim3(B * (D / ROWS)), dim3(1024), 0, stream>>>(enc, dur, out);
}

// Round 17
// 16.986 us; speedup vs baseline: 1.0394x; 1.0394x over previous
//
#include <hip/hip_runtime.h>

// Problem constants (fixed by the bench: B=8, L=512, T=4096, D=512).
constexpr int B = 8;
constexpr int L = 512;
constexpr int D = 512;
constexpr int T = 4096;
constexpr int ROWS = 4;                   // d-rows per block (contiguous 64 KB span)

constexpr int OUT_REP = B * D * T;        // offset of repeats in d_out
constexpr int OUT_LAT = OUT_REP + B * L;  // offset of latent_lengths

// R17 = R15 verbatim (the measured optimum; R16's 128 KB/1024-thread variant
// was 0.75 us slower). Grain curve mapped: 0.5K->20.45, 32K->17.68,
// 64K->16.91 (best), 128K->17.66. T_k ~= 13.6 us = 88% of copy ceiling,
// within ~1% of the structural model (drain 11.7 + preamble + ramp).
__global__ __launch_bounds__(512, 8) void encoder_expand_kernel(
    const float* __restrict__ enc,   // (B, D, L)
    const float* __restrict__ dur,   // (B, L)
    float* __restrict__ out)         // [expanded (B,D,T) | repeats (B,L) | latent (B)]
{
    const int bid = blockIdx.x;
    const int b   = bid >> 7;               // 0..7
    const int rp  = bid & 127;              // row group (d = 4*rp .. 4*rp+3)
    const int tid = threadIdx.x;            // 0..511
    const int lane = tid & 63;
    const int wave = tid >> 6;              // 0..7

    __shared__ unsigned short lut[T];       // 8 KB  t -> l, 0xFFFF = past end
    __shared__ float rows[ROWS * L];        // 8 KB  staged enc rows
    __shared__ int wave_tot[8];

    // ---- issue global loads first (independent) ----
    const float dv = dur[b * L + tid];      // 2 KB coalesced (tid spans L)
    const float* encp = enc + ((size_t)b * D + ROWS * rp) * L;  // 4 rows, contiguous
    const float4 rv = reinterpret_cast<const float4*>(encp)[tid];  // 8 KB coalesced

    // ---- init LUT sentinel (512 x 16 B) while loads are in flight ----
    reinterpret_cast<int4*>(lut)[tid] = make_int4(-1, -1, -1, -1);

    // ---- stage enc rows ----
    reinterpret_cast<float4*>(rows)[tid] = rv;

    // ---- repeats + scan over L=512 (1 elem/thread) ----
    const int r = (int)floorf(dv + 0.5f);

    int scan = r;                           // wave-level inclusive scan
    #pragma unroll
    for (int off = 1; off < 64; off <<= 1) {
        int n = __shfl_up(scan, off, 64);
        if (lane >= off) scan += n;
    }
    if (lane == 63) wave_tot[wave] = scan;
    __syncthreads();                        // lut init + rows + wave_tot visible

    int wpre = 0;
    #pragma unroll
    for (int w = 0; w < 8; ++w) wpre += (w < wave) ? wave_tot[w] : 0;
    int k = wpre + scan - r;                // exclusive prefix = t-start of l's span
    int total = 0;
    #pragma unroll
    for (int w = 0; w < 8; ++w) total += wave_tot[w];

    // ---- scatter: each l writes its own span (disjoint ranges, no race) ----
    for (int q = 0; q < r; ++q, ++k) if (k < T) lut[k] = (unsigned short)tid;

    // ---- side outputs (one block per batch) ----
    if (rp == 0) {
        out[OUT_REP + b * L + tid] = (float)r;
        if (tid == 0) out[OUT_LAT + b] = (float)total;
    }
    __syncthreads();                        // scatter done

    // ---- payload: 64 KB contiguous span = 4 rows x 2 halves of 8 KB,
    //      LUT read once per half, indices shared by all 4 rows ----
    float4* out4 = reinterpret_cast<float4*>(out + ((size_t)b * D + ROWS * rp) * T);

    const uint2 lu0 = *reinterpret_cast<const uint2*>(&lut[4 * tid]);         // h=0
    const uint2 lu1 = *reinterpret_cast<const uint2*>(&lut[2048 + 4 * tid]);  // h=1
    const int la0 = lu0.x & 0xffff, lb0 = lu0.x >> 16;
    const int lc0 = lu0.y & 0xffff, ld0 = lu0.y >> 16;
    const int la1 = lu1.x & 0xffff, lb1 = lu1.x >> 16;
    const int lc1 = lu1.y & 0xffff, ld1 = lu1.y >> 16;
    const bool z1 = (total <= 2048);        // whole h=1 half past latent_length

    #pragma unroll
    for (int rr = 0; rr < ROWS; ++rr) {
        const float* rowp = rows + rr * L;

        // h = 0 (t = 4*tid)
        float4 v0;
        v0.x = rowp[la0 & 511];             // monotone l across lanes: ~2-way banks
        v0.y = rowp[lb0 & 511];
        v0.z = rowp[lc0 & 511];
        v0.w = rowp[ld0 & 511];
        if (la0 == 0xffff) v0.x = 0.0f;
        if (lb0 == 0xffff) v0.y = 0.0f;
        if (lc0 == 0xffff) v0.z = 0.0f;
        if (ld0 == 0xffff) v0.w = 0.0f;
        out4[rr * 1024 + tid] = v0;         // block-wide 8 KB sequential store

        // h = 1 (t = 2048 + 4*tid)
        float4 v1 = make_float4(0.f, 0.f, 0.f, 0.f);
        if (!z1) {
            v1.x = rowp[la1 & 511];
            v1.y = rowp[lb1 & 511];
            v1.z = rowp[lc1 & 511];
            v1.w = rowp[ld1 & 511];
            if (la1 == 0xffff) v1.x = 0.0f;
            if (lb1 == 0xffff) v1.y = 0.0f;
            if (lc1 == 0xffff) v1.z = 0.0f;
            if (ld1 == 0xffff) v1.w = 0.0f;
        }
        out4[rr * 1024 + 512 + tid] = v1;
    }
}

extern "C" void kernel_launch(void* const* d_in, const int* in_sizes, int n_in,
                              void* d_out, int out_size, void* d_ws, size_t ws_size,
                              hipStream_t stream) {
    const float* enc = (const float*)d_in[0];   // (B, D, L) fp32
    const float* dur = (const float*)d_in[1];   // (B, L)    fp32
    float* out = (float*)d_out;
    encoder_expand_kernel<<<dim3(B * (D / ROWS)), dim3(512), 0, stream>>>(enc, dur, out);
}